// Round 15
// baseline (207.693 us; speedup 1.0000x reference)
//
#include <hip/hip_runtime.h>
#include <hip/hip_bf16.h>

// MHA: B=4, L=2048, D=1024, H=16, DK=64
// out = W_o-proj( softmax( (q Wq^T)(k Wk^T)^T / 8 ) (v Wv^T) )

typedef unsigned short u16;
typedef float f32x4  __attribute__((ext_vector_type(4)));
typedef float f32x16 __attribute__((ext_vector_type(16)));
typedef short s16x8  __attribute__((ext_vector_type(8)));
typedef unsigned u32x4 __attribute__((ext_vector_type(4)));
typedef __bf16 bf16x8 __attribute__((ext_vector_type(8)));

#define QSCL 0.18033688011112042f   // 0.125 * log2(e)  (folded into Wq)

__device__ __forceinline__ u16 f2b(float f) {
    union { float f; unsigned u; } x; x.f = f;
    unsigned r = x.u + 0x7fffu + ((x.u >> 16) & 1u);   // RNE
    return (u16)(r >> 16);
}

__device__ __forceinline__ f32x4 MF(s16x8 a, s16x8 b, f32x4 c) {
    return __builtin_amdgcn_mfma_f32_16x16x32_bf16(
        __builtin_bit_cast(bf16x8, a), __builtin_bit_cast(bf16x8, b), c, 0, 0, 0);
}
__device__ __forceinline__ f32x16 MF32(s16x8 a, s16x8 b, f32x16 c) {
    return __builtin_amdgcn_mfma_f32_32x32x16_bf16(
        __builtin_bit_cast(bf16x8, a), __builtin_bit_cast(bf16x8, b), c, 0, 0, 0);
}
__device__ __forceinline__ unsigned cvtpk(float lo, float hi) {
    unsigned r;
    asm("v_cvt_pk_bf16_f32 %0, %1, %2" : "=v"(r) : "v"(lo), "v"(hi));
    return r;
}
__device__ __forceinline__ void swap32(unsigned &a, unsigned &b) {
    asm volatile("v_permlane32_swap_b32 %0, %1" : "+v"(a), "+v"(b));
}
__device__ __forceinline__ float expa(float x) {      // raw v_exp_f32 (2^x)
    float r;
    asm("v_exp_f32 %0, %1" : "=v"(r) : "v"(x));
    return r;
}
// async global -> LDS, 16B per lane; dest = wave-uniform base + lane*16
__device__ __forceinline__ void g2l16(const u16* g, u16* lbase) {
    __builtin_amdgcn_global_load_lds((const __attribute__((address_space(1))) void*)g,
                                     (__attribute__((address_space(3))) void*)lbase, 16, 0, 0);
}

// ---------------------------------------------------------------------------
// Fused: blocks 0..255 compute mask tile flags; blocks 256+ convert fp32->bf16
// (q,k,v -> Abf[3][8192][1024]; Wq*QSCL,Wk,Wv,Wo -> Wbf[4][1024][1024]).
// ---------------------------------------------------------------------------
__global__ __launch_bounds__(256)
void convert_and_mask(const float* __restrict__ q, const float* __restrict__ k,
                      const float* __restrict__ v, const float* __restrict__ Wq,
                      const float* __restrict__ Wk, const float* __restrict__ Wv,
                      const float* __restrict__ Wo, const int* __restrict__ mask,
                      u16* __restrict__ Abf, u16* __restrict__ Wbf,
                      int* __restrict__ mflag) {
    if (blockIdx.x < 256) {                       // ---- mask tile flags ----
        __shared__ int anyz;
        if (threadIdx.x == 0) anyz = 0;
        __syncthreads();
        const int qt = blockIdx.x >> 4, kt = blockIdx.x & 15;
        int local = 0;
#pragma unroll
        for (int qq = 0; qq < 16; ++qq) {
            int e4 = qq * 256 + threadIdx.x;
            int r = e4 >> 5, cc = (e4 & 31) * 4;
            int4 mv = *(const int4*)(mask + (size_t)(qt * 128 + r) * 2048 + kt * 128 + cc);
            local |= (mv.x == 0) | (mv.y == 0) | (mv.z == 0) | (mv.w == 0);
        }
        if (local) atomicOr(&anyz, 1);
        __syncthreads();
        if (threadIdx.x == 0) mflag[blockIdx.x] = anyz;
        return;
    }
    // ---- fp32 -> bf16 conversion ----
    const size_t NQKV = 25165824;   // 3*8192*1024
    const size_t NCH  = 3670016;    // (NQKV + 4M) / 8
    const size_t nconv = (size_t)(gridDim.x - 256) * 256;
    for (size_t cidx = (size_t)(blockIdx.x - 256) * 256 + threadIdx.x; cidx < NCH;
         cidx += nconv) {
        size_t e = cidx * 8;
        const float* src; u16* dst; float scl = 1.f;
        if (e < NQKV) {
            src = (e < 8388608) ? q + e
                : (e < 16777216) ? k + (e - 8388608) : v + (e - 16777216);
            dst = Abf + e;
        } else {
            size_t o = e - NQKV;
            if (o < 1048576)      { src = Wq + o; scl = QSCL; }
            else if (o < 2097152) { src = Wk + (o - 1048576); }
            else if (o < 3145728) { src = Wv + (o - 2097152); }
            else                  { src = Wo + (o - 3145728); }
            dst = Wbf + o;
        }
        float4 a = *(const float4*)(src);
        float4 b = *(const float4*)(src + 4);
        ushort4 p0, p1;
        p0.x = f2b(a.x * scl); p0.y = f2b(a.y * scl);
        p0.z = f2b(a.z * scl); p0.w = f2b(a.w * scl);
        p1.x = f2b(b.x * scl); p1.y = f2b(b.y * scl);
        p1.z = f2b(b.z * scl); p1.w = f2b(b.w * scl);
        *(ushort4*)dst = p0; *(ushort4*)(dst + 4) = p1;
    }
}

// ---------------------------------------------------------------------------
// m97-style all-bf16 GEMM, 128x64 tile (acc halved -> 32 AGPR; unified regs
// ~<=128 -> 4 waves/SIMD via __launch_bounds__(256,4); 2x blocks for drain
// overlap). BK=32, linear LDS, global_load_lds. Grid (64,16,3): x = m-panel,
// y = n-panel -> blocks sharing an A-panel are m (mod 8) -> same XCD.
// Epilogues: z=0 Qh row-major head layout; z=1 Kf fragment; z=2 Vf fragment.
// ---------------------------------------------------------------------------
__global__ __launch_bounds__(256, 4)
void gemm_qkv_fast(const u16* __restrict__ Abf, const u16* __restrict__ Wbf,
                   u16* __restrict__ Qh, u16* __restrict__ Kf, u16* __restrict__ Vf) {
    __shared__ __align__(16) u16 As[128 * 32];   // 8 KB
    __shared__ __align__(16) u16 Bs[64 * 32];    // 4 KB
    const int z = blockIdx.z;
    const u16* A = Abf + (size_t)z * (8192 * 1024);
    const u16* W = Wbf + (size_t)z * (1024 * 1024);
    const int tid = threadIdx.x, l = tid & 63, w = tid >> 6;
    const int g = l >> 4, c = l & 15;
    const int m0 = blockIdx.x * 128, n0 = blockIdx.y * 64;
    const int wr = (w >> 1) * 64, wc = (w & 1) * 32;

    f32x4 acc[4][2];
#pragma unroll
    for (int i = 0; i < 4; ++i)
#pragma unroll
        for (int j = 0; j < 2; ++j)
#pragma unroll
            for (int e = 0; e < 4; ++e) acc[i][j][e] = 0.f;

    const u16* Ag = A + (size_t)(m0 + w * 32 + (l >> 2)) * 1024 + (l & 3) * 8;
    const u16* Wg = W + (size_t)(n0 + w * 16 + (l >> 2)) * 1024 + (l & 3) * 8;
    u16* Al = As + w * 1024;
    u16* Bl = Bs + w * 512;

    for (int kt = 0; kt < 32; ++kt) {
        __syncthreads();
        g2l16(Ag + kt * 32,         Al);
        g2l16(Ag + kt * 32 + 16384, Al + 512);   // +16 rows
        g2l16(Wg + kt * 32,         Bl);          // wave stages 16 B-rows
        __syncthreads();
        s16x8 af[4], bf[2];
#pragma unroll
        for (int i = 0; i < 4; ++i)
            af[i] = *(const s16x8*)(As + (wr + i * 16 + c) * 32 + g * 8);
#pragma unroll
        for (int i = 0; i < 2; ++i)
            bf[i] = *(const s16x8*)(Bs + (wc + i * 16 + c) * 32 + g * 8);
#pragma unroll
        for (int mi = 0; mi < 4; ++mi)
#pragma unroll
            for (int ni = 0; ni < 2; ++ni)
                acc[mi][ni] = MF(af[mi], bf[ni], acc[mi][ni]);
    }

    if (z == 0) {
#pragma unroll
        for (int mi = 0; mi < 4; ++mi)
#pragma unroll
            for (int ni = 0; ni < 2; ++ni)
#pragma unroll
                for (int j = 0; j < 4; ++j) {
                    int row = m0 + wr + mi * 16 + g * 4 + j;
                    int col = n0 + wc + ni * 16 + c;
                    int b = row >> 11, sl = row & 2047;
                    int h = col >> 6, d = col & 63;
                    Qh[(((size_t)(b * 16 + h)) * 2048 + sl) * 64 + d] = f2b(acc[mi][ni][j]);
                }
    } else if (z == 1) {
#pragma unroll
        for (int mi = 0; mi < 4; ++mi)
#pragma unroll
            for (int ni = 0; ni < 2; ++ni)
#pragma unroll
                for (int j = 0; j < 4; ++j) {
                    int row = m0 + wr + mi * 16 + g * 4 + j;   // key token
                    int col = n0 + wc + ni * 16 + c;
                    int b = row >> 11, kk = row & 2047;
                    int h = col >> 6, d = col & 63;
                    size_t off = (size_t)(b * 16 + h) * 131072
                               + (size_t)(((kk >> 5) * 4 + (d >> 4))) * 512
                               + ((kk & 31) + 32 * ((d >> 3) & 1)) * 8 + (d & 7);
                    Kf[off] = f2b(acc[mi][ni][j]);
                }
    } else {
#pragma unroll
        for (int mi = 0; mi < 4; ++mi)
#pragma unroll
            for (int ni = 0; ni < 2; ++ni) {
                int key0 = m0 + wr + mi * 16 + g * 4;          // 4 consecutive keys
                int col  = n0 + wc + ni * 16 + c;
                int b = key0 >> 11, kk0 = key0 & 2047;
                int h = col >> 6, d = col & 63;
                size_t off = (size_t)(b * 16 + h) * 131072
                           + (size_t)((kk0 >> 6) * 8 + (d >> 5) * 4 + ((kk0 >> 4) & 3)) * 512
                           + (((kk0 >> 3) & 1) * 32 + (d & 31)) * 8 + (kk0 & 7);
                ushort4 pk;
                pk.x = f2b(acc[mi][ni][0]); pk.y = f2b(acc[mi][ni][1]);
                pk.z = f2b(acc[mi][ni][2]); pk.w = f2b(acc[mi][ni][3]);
                *(ushort4*)(Vf + off) = pk;
            }
    }
}

// ---------------------------------------------------------------------------
// m97-style output projection (round-13 proven): A = attnB bf16, W bf16,
// C fp32. Grid (64,8); __launch_bounds__(256,3).
// ---------------------------------------------------------------------------
__global__ __launch_bounds__(256, 3)
void gemm_out_fast(const u16* __restrict__ Ab, const u16* __restrict__ W,
                   float* __restrict__ Cout) {
    __shared__ __align__(16) u16 As[128 * 32];
    __shared__ __align__(16) u16 Bs[128 * 32];
    const int tid = threadIdx.x, l = tid & 63, w = tid >> 6;
    const int g = l >> 4, c = l & 15;
    const int m0 = blockIdx.x * 128, n0 = blockIdx.y * 128;
    const int wr = (w >> 1) * 64, wc = (w & 1) * 64;

    f32x4 acc[4][4];
#pragma unroll
    for (int i = 0; i < 4; ++i)
#pragma unroll
        for (int j = 0; j < 4; ++j)
#pragma unroll
            for (int e = 0; e < 4; ++e) acc[i][j][e] = 0.f;

    const u16* Ag = Ab + (size_t)(m0 + w * 32 + (l >> 2)) * 1024 + (l & 3) * 8;
    const u16* Wg = W  + (size_t)(n0 + w * 32 + (l >> 2)) * 1024 + (l & 3) * 8;
    u16* Al = As + w * 1024;
    u16* Bl = Bs + w * 1024;

    for (int kt = 0; kt < 32; ++kt) {
        __syncthreads();
        g2l16(Ag + kt * 32,         Al);
        g2l16(Ag + kt * 32 + 16384, Al + 512);
        g2l16(Wg + kt * 32,         Bl);
        g2l16(Wg + kt * 32 + 16384, Bl + 512);
        __syncthreads();
        s16x8 af[4], bf[4];
#pragma unroll
        for (int i = 0; i < 4; ++i) {
            af[i] = *(const s16x8*)(As + (wr + i * 16 + c) * 32 + g * 8);
            bf[i] = *(const s16x8*)(Bs + (wc + i * 16 + c) * 32 + g * 8);
        }
#pragma unroll
        for (int mi = 0; mi < 4; ++mi)
#pragma unroll
            for (int ni = 0; ni < 4; ++ni)
                acc[mi][ni] = MF(af[mi], bf[ni], acc[mi][ni]);
    }

#pragma unroll
    for (int mi = 0; mi < 4; ++mi)
#pragma unroll
        for (int ni = 0; ni < 4; ++ni)
#pragma unroll
            for (int j = 0; j < 4; ++j) {
                int row = m0 + wr + mi * 16 + g * 4 + j;
                int col = n0 + wc + ni * 16 + c;
                Cout[(size_t)row * 1024 + col] = acc[mi][ni][j];
            }
}

// ---------------------------------------------------------------------------
// Flash attention v8 (round-13 proven, unchanged): 8 waves x 32 q-rows,
// 128-key super-tiles, fragment-order K/V via global_load_lds, dbuf,
// deferred-PV carry, MFMA-ones lsum. Grid (B*H=64, L/256=8), 512 threads.
// ---------------------------------------------------------------------------
__global__ __launch_bounds__(512, 4)
void flash_attn(const u16* __restrict__ Qh, const u16* __restrict__ Kf,
                const u16* __restrict__ Vf, const int* __restrict__ mask,
                const int* __restrict__ mflag, u16* __restrict__ attnB) {
    __shared__ __align__(16) u16 KV[2][2][16][512];  // [dbuf][K/V][region][lane*8]

    const int tid = threadIdx.x, w = tid >> 6, l = tid & 63;
    const int hi = l >> 5, q32 = l & 31;
    const int bh = blockIdx.x, qt = blockIdx.y;
    const size_t base = (size_t)bh * (2048 * 64);
    const u16* Qp = Qh + base;
    const u16* Kp = Kf + base;
    const u16* Vp = Vf + base;
    const int qrow_w = qt * 256 + w * 32;            // this wave's 32 q-rows

    const int flagrow = qt * 2 + (w >> 2);           // 128-row mask-tile row
    int anyflag = 0;                                  // hoisted mask gate
#pragma unroll
    for (int i = 0; i < 16; ++i) anyflag |= mflag[flagrow * 16 + i];

    s16x8 Qf[4];
#pragma unroll
    for (int s = 0; s < 4; ++s)
        Qf[s] = *(const s16x8*)(Qp + (size_t)(qrow_w + q32) * 64 + s * 16 + hi * 8);

    s16x8 ones;                                       // bf16 1.0 splat
#pragma unroll
    for (int i = 0; i < 8; ++i) ones[i] = (short)0x3F80;

    f32x16 z16;
#pragma unroll
    for (int r = 0; r < 16; ++r) z16[r] = 0.f;
    f32x16 oA = z16, oB = z16, lacc = z16;

    auto stage = [&](int buf, int st) {
        const u16* ks = Kp + (size_t)(st * 16 + w * 2) * 512 + l * 8;
        const u16* vs = Vp + (size_t)(st * 16 + w * 2) * 512 + l * 8;
        g2l16(ks,       &KV[buf][0][w * 2][0]);
        g2l16(ks + 512, &KV[buf][0][w * 2 + 1][0]);
        g2l16(vs,       &KV[buf][1][w * 2][0]);
        g2l16(vs + 512, &KV[buf][1][w * 2 + 1][0]);
    };

    auto Shalf = [&](int buf, int h) -> f32x16 {
        const int rb = (h >> 1) * 8 + (h & 1) * 4;
        __builtin_amdgcn_s_setprio(1);
        s16x8 ka = *(const s16x8*)&KV[buf][0][rb][l * 8];
        f32x16 s = MF32(ka, Qf[0], z16);
#pragma unroll
        for (int ss = 1; ss < 4; ++ss) {
            ka = *(const s16x8*)&KV[buf][0][rb + ss][l * 8];
            s = MF32(ka, Qf[ss], s);
        }
        __builtin_amdgcn_s_setprio(0);
        return s;
    };
    auto expmask = [&](f32x16& s, int st, int h) {
        if (anyflag && mflag[flagrow * 16 + st] != 0) {
            const int qr = qrow_w + q32, kb = st * 128 + h * 32;
#pragma unroll
            for (int r = 0; r < 16; ++r) {
                int key = (r & 3) + 8 * (r >> 2) + 4 * hi;
                if (mask[(size_t)qr * 2048 + kb + key] == 0) s[r] = -1e30f;
            }
        }
#pragma unroll
        for (int r = 0; r < 16; ++r) s[r] = expa(s[r]);
    };
    auto packh = [&](const f32x16& s, s16x8& X0, s16x8& X1) {
        u32x4 t;
        unsigned a0 = cvtpk(s[0], s[1]),   a1 = cvtpk(s[2], s[3]);
        unsigned b0 = cvtpk(s[4], s[5]),   b1 = cvtpk(s[6], s[7]);
        swap32(a0, b0); swap32(a1, b1);
        t.x = a0; t.y = a1; t.z = b0; t.w = b1;
        X0 = __builtin_bit_cast(s16x8, t);
        unsigned c0 = cvtpk(s[8], s[9]),   c1 = cvtpk(s[10], s[11]);
        unsigned d0 = cvtpk(s[12], s[13]), d1 = cvtpk(s[14], s[15]);
        swap32(c0, d0); swap32(c1, d1);
        t.x = c0; t.y = c1; t.z = d0; t.w = d1;
        X1 = __builtin_bit_cast(s16x8, t);
    };
    auto PVhalf = [&](int buf, int h, s16x8 X0, s16x8 X1) {
        const int rb = (h >> 1) * 8, hb = (h & 1) * 2;
        __builtin_amdgcn_s_setprio(1);
        s16x8 v0 = *(const s16x8*)&KV[buf][1][rb + hb][l * 8];
        s16x8 v1 = *(const s16x8*)&KV[buf][1][rb + 4 + hb][l * 8];
        oA = MF32(X0, v0, oA);
        oB = MF32(X0, v1, oB);
        lacc = MF32(X0, ones, lacc);
        s16x8 v2 = *(const s16x8*)&KV[buf][1][rb + hb + 1][l * 8];
        s16x8 v3 = *(const s16x8*)&KV[buf][1][rb + 4 + hb + 1][l * 8];
        oA = MF32(X1, v2, oA);
        oB = MF32(X1, v3, oB);
        lacc = MF32(X1, ones, lacc);
        __builtin_amdgcn_s_setprio(0);
    };

    s16x8 Xc0, Xc1;                                   // carried Xp (prev half 3)

    auto processST = [&](int buf, int st) {
        f32x16 sp = Shalf(buf, 0);
        expmask(sp, st, 0);
#pragma unroll
        for (int h = 1; h < 4; ++h) {
            f32x16 sc = Shalf(buf, h);
            s16x8 Y0, Y1;
            packh(sp, Y0, Y1);
            PVhalf(buf, h - 1, Y0, Y1);               // overlaps expmask(sc)
            expmask(sc, st, h);
            sp = sc;
        }
        packh(sp, Xc0, Xc1);
    };

    stage(0, 0);
    __syncthreads();                                  // tile 0 ready
    stage(1, 1);                                      // prefetch tile 1
    processST(0, 0);

    for (int st = 1; st < 16; ++st) {
        const int buf = st & 1;
        PVhalf(buf ^ 1, 3, Xc0, Xc1);                 // deferred PV of (st-1, h3)
        __syncthreads();                              // stage(st) drained; buf^1 free
        if (st < 15) stage(buf ^ 1, st + 1);
        processST(buf, st);
    }
    PVhalf(1, 3, Xc0, Xc1);                           // epilogue: (15, h3)

    const int b = bh >> 4, h = bh & 15;
#pragma unroll
    for (int r = 0; r < 16; ++r) {
        int qloc = (r & 3) + 8 * (r >> 2) + 4 * hi;
        float inv = __builtin_amdgcn_rcpf(lacc[r]);   // row-sum already in-lane
        int row = qrow_w + qloc;
        u16* dst = attnB + ((size_t)b * 2048 + row) * 1024 + h * 64 + q32;
        dst[0]  = f2b(oA[r] * inv);
        dst[32] = f2b(oB[r] * inv);
    }
}

// ---------------------------------------------------------------------------
extern "C" void kernel_launch(void* const* d_in, const int* in_sizes, int n_in,
                              void* d_out, int out_size, void* d_ws, size_t ws_size,
                              hipStream_t stream) {
    const float* q    = (const float*)d_in[0];
    const float* k    = (const float*)d_in[1];
    const float* v    = (const float*)d_in[2];
    const int*   mask = (const int*)d_in[3];
    const float* Wq   = (const float*)d_in[4];
    const float* Wk   = (const float*)d_in[5];
    const float* Wv   = (const float*)d_in[6];
    const float* Wo   = (const float*)d_in[7];

    char* ws = (char*)d_ws;
    u16* Abf   = (u16*)(ws);                       // 48 MB [3][8192][1024]
    u16* Wbf   = (u16*)(ws + (48u << 20));         // 8 MB  [4][1024][1024]
    u16* Qh    = (u16*)(ws + (56u << 20));         // 16 MB [bh][L][64]
    u16* Kf    = (u16*)(ws + (72u << 20));         // 16 MB fragment layout
    u16* Vf    = (u16*)(ws + (88u << 20));         // 16 MB fragment layout
    u16* attnB = (u16*)(ws);                       // 16 MB, reuses dead Abf
    int* mflag = (int*)(ws + (104u << 20));        // 1 KB

    convert_and_mask<<<dim3(2304), dim3(256), 0, stream>>>(q, k, v, Wq, Wk, Wv, Wo,
                                                           mask, Abf, Wbf, mflag);
    gemm_qkv_fast<<<dim3(64, 16, 3), dim3(256), 0, stream>>>(Abf, Wbf, Qh, Kf, Vf);
    flash_attn<<<dim3(64, 8), dim3(512), 0, stream>>>(Qh, Kf, Vf, mask, mflag, attnB);
    gemm_out_fast<<<dim3(64, 8), dim3(256), 0, stream>>>(attnB, Wbf + 3145728, (float*)d_out);
}

// Round 16
// 192.068 us; speedup vs baseline: 1.0814x; 1.0814x over previous
//
#include <hip/hip_runtime.h>
#include <hip/hip_bf16.h>

// MHA: B=4, L=2048, D=1024, H=16, DK=64
// out = W_o-proj( softmax( (q Wq^T)(k Wk^T)^T / 8 ) (v Wv^T) )

typedef unsigned short u16;
typedef float f32x4  __attribute__((ext_vector_type(4)));
typedef float f32x16 __attribute__((ext_vector_type(16)));
typedef short s16x8  __attribute__((ext_vector_type(8)));
typedef unsigned u32x4 __attribute__((ext_vector_type(4)));
typedef __bf16 bf16x8 __attribute__((ext_vector_type(8)));

#define QSCL 0.18033688011112042f   // 0.125 * log2(e)  (folded into Wq)

__device__ __forceinline__ u16 f2b(float f) {
    union { float f; unsigned u; } x; x.f = f;
    unsigned r = x.u + 0x7fffu + ((x.u >> 16) & 1u);   // RNE
    return (u16)(r >> 16);
}

__device__ __forceinline__ f32x4 MF(s16x8 a, s16x8 b, f32x4 c) {
    return __builtin_amdgcn_mfma_f32_16x16x32_bf16(
        __builtin_bit_cast(bf16x8, a), __builtin_bit_cast(bf16x8, b), c, 0, 0, 0);
}
__device__ __forceinline__ f32x16 MF32(s16x8 a, s16x8 b, f32x16 c) {
    return __builtin_amdgcn_mfma_f32_32x32x16_bf16(
        __builtin_bit_cast(bf16x8, a), __builtin_bit_cast(bf16x8, b), c, 0, 0, 0);
}
__device__ __forceinline__ unsigned cvtpk(float lo, float hi) {
    unsigned r;
    asm("v_cvt_pk_bf16_f32 %0, %1, %2" : "=v"(r) : "v"(lo), "v"(hi));
    return r;
}
__device__ __forceinline__ void swap32(unsigned &a, unsigned &b) {
    asm volatile("v_permlane32_swap_b32 %0, %1" : "+v"(a), "+v"(b));
}
__device__ __forceinline__ float expa(float x) {      // raw v_exp_f32 (2^x)
    float r;
    asm("v_exp_f32 %0, %1" : "=v"(r) : "v"(x));
    return r;
}
// async global -> LDS, 16B per lane; dest = wave-uniform base + lane*16
__device__ __forceinline__ void g2l16(const u16* g, u16* lbase) {
    __builtin_amdgcn_global_load_lds((const __attribute__((address_space(1))) void*)g,
                                     (__attribute__((address_space(3))) void*)lbase, 16, 0, 0);
}

// ---------------------------------------------------------------------------
// Fused: blocks 0..255 compute mask tile flags; blocks 256+ convert fp32->bf16
// (q,k,v -> Abf[3][8192][1024]; Wq*QSCL,Wk,Wv,Wo -> Wbf[4][1024][1024]).
// ---------------------------------------------------------------------------
__global__ __launch_bounds__(256)
void convert_and_mask(const float* __restrict__ q, const float* __restrict__ k,
                      const float* __restrict__ v, const float* __restrict__ Wq,
                      const float* __restrict__ Wk, const float* __restrict__ Wv,
                      const float* __restrict__ Wo, const int* __restrict__ mask,
                      u16* __restrict__ Abf, u16* __restrict__ Wbf,
                      int* __restrict__ mflag) {
    if (blockIdx.x < 256) {                       // ---- mask tile flags ----
        __shared__ int anyz;
        if (threadIdx.x == 0) anyz = 0;
        __syncthreads();
        const int qt = blockIdx.x >> 4, kt = blockIdx.x & 15;
        int local = 0;
#pragma unroll
        for (int qq = 0; qq < 16; ++qq) {
            int e4 = qq * 256 + threadIdx.x;
            int r = e4 >> 5, cc = (e4 & 31) * 4;
            int4 mv = *(const int4*)(mask + (size_t)(qt * 128 + r) * 2048 + kt * 128 + cc);
            local |= (mv.x == 0) | (mv.y == 0) | (mv.z == 0) | (mv.w == 0);
        }
        if (local) atomicOr(&anyz, 1);
        __syncthreads();
        if (threadIdx.x == 0) mflag[blockIdx.x] = anyz;
        return;
    }
    // ---- fp32 -> bf16 conversion ----
    const size_t NQKV = 25165824;   // 3*8192*1024
    const size_t NCH  = 3670016;    // (NQKV + 4M) / 8
    const size_t nconv = (size_t)(gridDim.x - 256) * 256;
    for (size_t cidx = (size_t)(blockIdx.x - 256) * 256 + threadIdx.x; cidx < NCH;
         cidx += nconv) {
        size_t e = cidx * 8;
        const float* src; u16* dst; float scl = 1.f;
        if (e < NQKV) {
            src = (e < 8388608) ? q + e
                : (e < 16777216) ? k + (e - 8388608) : v + (e - 16777216);
            dst = Abf + e;
        } else {
            size_t o = e - NQKV;
            if (o < 1048576)      { src = Wq + o; scl = QSCL; }
            else if (o < 2097152) { src = Wk + (o - 1048576); }
            else if (o < 3145728) { src = Wv + (o - 2097152); }
            else                  { src = Wo + (o - 3145728); }
            dst = Wbf + o;
        }
        float4 a = *(const float4*)(src);
        float4 b = *(const float4*)(src + 4);
        ushort4 p0, p1;
        p0.x = f2b(a.x * scl); p0.y = f2b(a.y * scl);
        p0.z = f2b(a.z * scl); p0.w = f2b(a.w * scl);
        p1.x = f2b(b.x * scl); p1.y = f2b(b.y * scl);
        p1.z = f2b(b.z * scl); p1.w = f2b(b.w * scl);
        *(ushort4*)dst = p0; *(ushort4*)(dst + 4) = p1;
    }
}

// ---------------------------------------------------------------------------
// m97-style all-bf16 GEMM: 128x128 tile, BK=32, linear LDS, global_load_lds.
// Grid (64,8,3): x = m-panel, y = n-panel -> XCD-local A-panel reuse.
// __launch_bounds__(256,3): cap unified regs at 170 (108 VGPR + 64 AGPR was
// 172 -> 2 waves/SIMD; shaving 2 regs buys the 3rd wave = +50% latency hiding
// for the per-iter vmcnt drain).
// Epilogues: z=0 Qh row-major head layout; z=1 Kf fragment; z=2 Vf fragment.
// ---------------------------------------------------------------------------
__global__ __launch_bounds__(256, 3)
void gemm_qkv_fast(const u16* __restrict__ Abf, const u16* __restrict__ Wbf,
                   u16* __restrict__ Qh, u16* __restrict__ Kf, u16* __restrict__ Vf) {
    __shared__ __align__(16) u16 As[128 * 32];
    __shared__ __align__(16) u16 Bs[128 * 32];
    const int z = blockIdx.z;
    const u16* A = Abf + (size_t)z * (8192 * 1024);
    const u16* W = Wbf + (size_t)z * (1024 * 1024);
    const int tid = threadIdx.x, l = tid & 63, w = tid >> 6;
    const int g = l >> 4, c = l & 15;
    const int m0 = blockIdx.x * 128, n0 = blockIdx.y * 128;
    const int wr = (w >> 1) * 64, wc = (w & 1) * 64;

    f32x4 acc[4][4];
#pragma unroll
    for (int i = 0; i < 4; ++i)
#pragma unroll
        for (int j = 0; j < 4; ++j)
#pragma unroll
            for (int e = 0; e < 4; ++e) acc[i][j][e] = 0.f;

    const u16* Ag = A + (size_t)(m0 + w * 32 + (l >> 2)) * 1024 + (l & 3) * 8;
    const u16* Wg = W + (size_t)(n0 + w * 32 + (l >> 2)) * 1024 + (l & 3) * 8;
    u16* Al = As + w * 1024;
    u16* Bl = Bs + w * 1024;

    for (int kt = 0; kt < 32; ++kt) {
        __syncthreads();
        g2l16(Ag + kt * 32,         Al);
        g2l16(Ag + kt * 32 + 16384, Al + 512);
        g2l16(Wg + kt * 32,         Bl);
        g2l16(Wg + kt * 32 + 16384, Bl + 512);
        __syncthreads();
        s16x8 af[4], bf[4];
#pragma unroll
        for (int i = 0; i < 4; ++i) {
            af[i] = *(const s16x8*)(As + (wr + i * 16 + c) * 32 + g * 8);
            bf[i] = *(const s16x8*)(Bs + (wc + i * 16 + c) * 32 + g * 8);
        }
#pragma unroll
        for (int mi = 0; mi < 4; ++mi)
#pragma unroll
            for (int ni = 0; ni < 4; ++ni)
                acc[mi][ni] = MF(af[mi], bf[ni], acc[mi][ni]);
    }

    if (z == 0) {
#pragma unroll
        for (int mi = 0; mi < 4; ++mi)
#pragma unroll
            for (int ni = 0; ni < 4; ++ni)
#pragma unroll
                for (int j = 0; j < 4; ++j) {
                    int row = m0 + wr + mi * 16 + g * 4 + j;
                    int col = n0 + wc + ni * 16 + c;
                    int b = row >> 11, sl = row & 2047;
                    int h = col >> 6, d = col & 63;
                    Qh[(((size_t)(b * 16 + h)) * 2048 + sl) * 64 + d] = f2b(acc[mi][ni][j]);
                }
    } else if (z == 1) {
#pragma unroll
        for (int mi = 0; mi < 4; ++mi)
#pragma unroll
            for (int ni = 0; ni < 4; ++ni)
#pragma unroll
                for (int j = 0; j < 4; ++j) {
                    int row = m0 + wr + mi * 16 + g * 4 + j;   // key token
                    int col = n0 + wc + ni * 16 + c;
                    int b = row >> 11, kk = row & 2047;
                    int h = col >> 6, d = col & 63;
                    size_t off = (size_t)(b * 16 + h) * 131072
                               + (size_t)(((kk >> 5) * 4 + (d >> 4))) * 512
                               + ((kk & 31) + 32 * ((d >> 3) & 1)) * 8 + (d & 7);
                    Kf[off] = f2b(acc[mi][ni][j]);
                }
    } else {
#pragma unroll
        for (int mi = 0; mi < 4; ++mi)
#pragma unroll
            for (int ni = 0; ni < 4; ++ni) {
                int key0 = m0 + wr + mi * 16 + g * 4;          // 4 consecutive keys
                int col  = n0 + wc + ni * 16 + c;
                int b = key0 >> 11, kk0 = key0 & 2047;
                int h = col >> 6, d = col & 63;
                size_t off = (size_t)(b * 16 + h) * 131072
                           + (size_t)((kk0 >> 6) * 8 + (d >> 5) * 4 + ((kk0 >> 4) & 3)) * 512
                           + (((kk0 >> 3) & 1) * 32 + (d & 31)) * 8 + (kk0 & 7);
                ushort4 pk;
                pk.x = f2b(acc[mi][ni][0]); pk.y = f2b(acc[mi][ni][1]);
                pk.z = f2b(acc[mi][ni][2]); pk.w = f2b(acc[mi][ni][3]);
                *(ushort4*)(Vf + off) = pk;
            }
    }
}

// ---------------------------------------------------------------------------
// m97-style output projection: A = attnB bf16 [8192][1024], W bf16, C fp32.
// Grid (64,8); __launch_bounds__(256,3) for the same occupancy reason.
// ---------------------------------------------------------------------------
__global__ __launch_bounds__(256, 3)
void gemm_out_fast(const u16* __restrict__ Ab, const u16* __restrict__ W,
                   float* __restrict__ Cout) {
    __shared__ __align__(16) u16 As[128 * 32];
    __shared__ __align__(16) u16 Bs[128 * 32];
    const int tid = threadIdx.x, l = tid & 63, w = tid >> 6;
    const int g = l >> 4, c = l & 15;
    const int m0 = blockIdx.x * 128, n0 = blockIdx.y * 128;
    const int wr = (w >> 1) * 64, wc = (w & 1) * 64;

    f32x4 acc[4][4];
#pragma unroll
    for (int i = 0; i < 4; ++i)
#pragma unroll
        for (int j = 0; j < 4; ++j)
#pragma unroll
            for (int e = 0; e < 4; ++e) acc[i][j][e] = 0.f;

    const u16* Ag = Ab + (size_t)(m0 + w * 32 + (l >> 2)) * 1024 + (l & 3) * 8;
    const u16* Wg = W  + (size_t)(n0 + w * 32 + (l >> 2)) * 1024 + (l & 3) * 8;
    u16* Al = As + w * 1024;
    u16* Bl = Bs + w * 1024;

    for (int kt = 0; kt < 32; ++kt) {
        __syncthreads();
        g2l16(Ag + kt * 32,         Al);
        g2l16(Ag + kt * 32 + 16384, Al + 512);
        g2l16(Wg + kt * 32,         Bl);
        g2l16(Wg + kt * 32 + 16384, Bl + 512);
        __syncthreads();
        s16x8 af[4], bf[4];
#pragma unroll
        for (int i = 0; i < 4; ++i) {
            af[i] = *(const s16x8*)(As + (wr + i * 16 + c) * 32 + g * 8);
            bf[i] = *(const s16x8*)(Bs + (wc + i * 16 + c) * 32 + g * 8);
        }
#pragma unroll
        for (int mi = 0; mi < 4; ++mi)
#pragma unroll
            for (int ni = 0; ni < 4; ++ni)
                acc[mi][ni] = MF(af[mi], bf[ni], acc[mi][ni]);
    }

#pragma unroll
    for (int mi = 0; mi < 4; ++mi)
#pragma unroll
        for (int ni = 0; ni < 4; ++ni)
#pragma unroll
            for (int j = 0; j < 4; ++j) {
                int row = m0 + wr + mi * 16 + g * 4 + j;
                int col = n0 + wc + ni * 16 + c;
                Cout[(size_t)row * 1024 + col] = acc[mi][ni][j];
            }
}

// ---------------------------------------------------------------------------
// Flash attention v8: 8 waves x 32 q-rows = 256 q-rows/block; 128-key
// SUPER-TILES (2 kt) per barrier. K/V staged once per 256 q-rows; barrier
// count per wave halved. LDS 64 KB -> 2 blocks/CU -> 16 waves/CU (4/SIMD).
// Half-tile S -> exp -> pack -> PV with deferred-PV carry, MFMA-ones lsum,
// fragment-order K/V via global_load_lds, conflict-free.
// Grid (B*H=64, L/256=8), 512 threads = 8 waves.
// ---------------------------------------------------------------------------
__global__ __launch_bounds__(512, 4)
void flash_attn(const u16* __restrict__ Qh, const u16* __restrict__ Kf,
                const u16* __restrict__ Vf, const int* __restrict__ mask,
                const int* __restrict__ mflag, u16* __restrict__ attnB) {
    __shared__ __align__(16) u16 KV[2][2][16][512];  // [dbuf][K/V][region][lane*8]

    const int tid = threadIdx.x, w = tid >> 6, l = tid & 63;
    const int hi = l >> 5, q32 = l & 31;
    const int bh = blockIdx.x, qt = blockIdx.y;
    const size_t base = (size_t)bh * (2048 * 64);
    const u16* Qp = Qh + base;
    const u16* Kp = Kf + base;
    const u16* Vp = Vf + base;
    const int qrow_w = qt * 256 + w * 32;            // this wave's 32 q-rows

    const int flagrow = qt * 2 + (w >> 2);           // 128-row mask-tile row
    int anyflag = 0;                                  // hoisted mask gate
#pragma unroll
    for (int i = 0; i < 16; ++i) anyflag |= mflag[flagrow * 16 + i];

    s16x8 Qf[4];
#pragma unroll
    for (int s = 0; s < 4; ++s)
        Qf[s] = *(const s16x8*)(Qp + (size_t)(qrow_w + q32) * 64 + s * 16 + hi * 8);

    s16x8 ones;                                       // bf16 1.0 splat
#pragma unroll
    for (int i = 0; i < 8; ++i) ones[i] = (short)0x3F80;

    f32x16 z16;
#pragma unroll
    for (int r = 0; r < 16; ++r) z16[r] = 0.f;
    f32x16 oA = z16, oB = z16, lacc = z16;

    auto stage = [&](int buf, int st) {
        const u16* ks = Kp + (size_t)(st * 16 + w * 2) * 512 + l * 8;
        const u16* vs = Vp + (size_t)(st * 16 + w * 2) * 512 + l * 8;
        g2l16(ks,       &KV[buf][0][w * 2][0]);
        g2l16(ks + 512, &KV[buf][0][w * 2 + 1][0]);
        g2l16(vs,       &KV[buf][1][w * 2][0]);
        g2l16(vs + 512, &KV[buf][1][w * 2 + 1][0]);
    };

    auto Shalf = [&](int buf, int h) -> f32x16 {
        const int rb = (h >> 1) * 8 + (h & 1) * 4;
        __builtin_amdgcn_s_setprio(1);
        s16x8 ka = *(const s16x8*)&KV[buf][0][rb][l * 8];
        f32x16 s = MF32(ka, Qf[0], z16);
#pragma unroll
        for (int ss = 1; ss < 4; ++ss) {
            ka = *(const s16x8*)&KV[buf][0][rb + ss][l * 8];
            s = MF32(ka, Qf[ss], s);
        }
        __builtin_amdgcn_s_setprio(0);
        return s;
    };
    auto expmask = [&](f32x16& s, int st, int h) {
        if (anyflag && mflag[flagrow * 16 + st] != 0) {
            const int qr = qrow_w + q32, kb = st * 128 + h * 32;
#pragma unroll
            for (int r = 0; r < 16; ++r) {
                int key = (r & 3) + 8 * (r >> 2) + 4 * hi;
                if (mask[(size_t)qr * 2048 + kb + key] == 0) s[r] = -1e30f;
            }
        }
#pragma unroll
        for (int r = 0; r < 16; ++r) s[r] = expa(s[r]);
    };
    auto packh = [&](const f32x16& s, s16x8& X0, s16x8& X1) {
        u32x4 t;
        unsigned a0 = cvtpk(s[0], s[1]),   a1 = cvtpk(s[2], s[3]);
        unsigned b0 = cvtpk(s[4], s[5]),   b1 = cvtpk(s[6], s[7]);
        swap32(a0, b0); swap32(a1, b1);
        t.x = a0; t.y = a1; t.z = b0; t.w = b1;
        X0 = __builtin_bit_cast(s16x8, t);
        unsigned c0 = cvtpk(s[8], s[9]),   c1 = cvtpk(s[10], s[11]);
        unsigned d0 = cvtpk(s[12], s[13]), d1 = cvtpk(s[14], s[15]);
        swap32(c0, d0); swap32(c1, d1);
        t.x = c0; t.y = c1; t.z = d0; t.w = d1;
        X1 = __builtin_bit_cast(s16x8, t);
    };
    auto PVhalf = [&](int buf, int h, s16x8 X0, s16x8 X1) {
        const int rb = (h >> 1) * 8, hb = (h & 1) * 2;
        __builtin_amdgcn_s_setprio(1);
        s16x8 v0 = *(const s16x8*)&KV[buf][1][rb + hb][l * 8];
        s16x8 v1 = *(const s16x8*)&KV[buf][1][rb + 4 + hb][l * 8];
        oA = MF32(X0, v0, oA);
        oB = MF32(X0, v1, oB);
        lacc = MF32(X0, ones, lacc);
        s16x8 v2 = *(const s16x8*)&KV[buf][1][rb + hb + 1][l * 8];
        s16x8 v3 = *(const s16x8*)&KV[buf][1][rb + 4 + hb + 1][l * 8];
        oA = MF32(X1, v2, oA);
        oB = MF32(X1, v3, oB);
        lacc = MF32(X1, ones, lacc);
        __builtin_amdgcn_s_setprio(0);
    };

    s16x8 Xc0, Xc1;                                   // carried Xp (prev half 3)

    auto processST = [&](int buf, int st) {
        f32x16 sp = Shalf(buf, 0);
        expmask(sp, st, 0);
#pragma unroll
        for (int h = 1; h < 4; ++h) {
            f32x16 sc = Shalf(buf, h);
            s16x8 Y0, Y1;
            packh(sp, Y0, Y1);
            PVhalf(buf, h - 1, Y0, Y1);               // overlaps expmask(sc)
            expmask(sc, st, h);
            sp = sc;
        }
        packh(sp, Xc0, Xc1);
    };

    stage(0, 0);
    __syncthreads();                                  // tile 0 ready
    stage(1, 1);                                      // prefetch tile 1
    processST(0, 0);

    for (int st = 1; st < 16; ++st) {
        const int buf = st & 1;
        PVhalf(buf ^ 1, 3, Xc0, Xc1);                 // deferred PV of (st-1, h3)
        __syncthreads();                              // stage(st) drained; buf^1 free
        if (st < 15) stage(buf ^ 1, st + 1);
        processST(buf, st);
    }
    PVhalf(1, 3, Xc0, Xc1);                           // epilogue: (15, h3)

    const int b = bh >> 4, h = bh & 15;
#pragma unroll
    for (int r = 0; r < 16; ++r) {
        int qloc = (r & 3) + 8 * (r >> 2) + 4 * hi;
        float inv = __builtin_amdgcn_rcpf(lacc[r]);   // row-sum already in-lane
        int row = qrow_w + qloc;
        u16* dst = attnB + ((size_t)b * 2048 + row) * 1024 + h * 64 + q32;
        dst[0]  = f2b(oA[r] * inv);
        dst[32] = f2b(oB[r] * inv);
    }
}

// ---------------------------------------------------------------------------
extern "C" void kernel_launch(void* const* d_in, const int* in_sizes, int n_in,
                              void* d_out, int out_size, void* d_ws, size_t ws_size,
                              hipStream_t stream) {
    const float* q    = (const float*)d_in[0];
    const float* k    = (const float*)d_in[1];
    const float* v    = (const float*)d_in[2];
    const int*   mask = (const int*)d_in[3];
    const float* Wq   = (const float*)d_in[4];
    const float* Wk   = (const float*)d_in[5];
    const float* Wv   = (const float*)d_in[6];
    const float* Wo   = (const float*)d_in[7];

    char* ws = (char*)d_ws;
    u16* Abf   = (u16*)(ws);                       // 48 MB [3][8192][1024]
    u16* Wbf   = (u16*)(ws + (48u << 20));         // 8 MB  [4][1024][1024]
    u16* Qh    = (u16*)(ws + (56u << 20));         // 16 MB [bh][L][64]
    u16* Kf    = (u16*)(ws + (72u << 20));         // 16 MB fragment layout
    u16* Vf    = (u16*)(ws + (88u << 20));         // 16 MB fragment layout
    u16* attnB = (u16*)(ws);                       // 16 MB, reuses dead Abf
    int* mflag = (int*)(ws + (104u << 20));        // 1 KB

    convert_and_mask<<<dim3(2304), dim3(256), 0, stream>>>(q, k, v, Wq, Wk, Wv, Wo,
                                                           mask, Abf, Wbf, mflag);
    gemm_qkv_fast<<<dim3(64, 8, 3), dim3(256), 0, stream>>>(Abf, Wbf, Qh, Kf, Vf);
    flash_attn<<<dim3(64, 8), dim3(512), 0, stream>>>(Qh, Kf, Vf, mask, mflag, attnB);
    gemm_out_fast<<<dim3(64, 8), dim3(256), 0, stream>>>(attnB, Wbf + 3145728, (float*)d_out);
}